// Round 1
// baseline (93.169 us; speedup 1.0000x reference)
//
#include <hip/hip_runtime.h>

#define HH 1024
#define WW 1024
#define NPIX (HH*WW)
#define NB 64            // blocks per sample for full-pass kernels
#define ROWS_PER_BLK 16  // 1024/64

__device__ inline float waveReduceSum(float v){ for(int o=32;o;o>>=1) v += __shfl_down(v,o); return v; }
__device__ inline float waveReduceMin(float v){ for(int o=32;o;o>>=1) v = fminf(v,__shfl_down(v,o)); return v; }
__device__ inline float waveReduceMax(float v){ for(int o=32;o;o>>=1) v = fmaxf(v,__shfl_down(v,o)); return v; }

// Pass 1: per-block partials of {min, max, sum|sigmoid-0.5|, count(x>0)}
__global__ __launch_bounds__(256) void k_stats1(const float* __restrict__ x, float* __restrict__ p1){
  int s = blockIdx.x >> 6, blk = blockIdx.x & 63;
  int t = threadIdx.x;
  const float4* xp = (const float4*)(x + (size_t)s*NPIX + (size_t)blk*(NPIX/NB));
  float vmin = INFINITY, vmax = -INFINITY, sabs = 0.f, cnt = 0.f;
  #pragma unroll
  for(int i=0;i<16;i++){
    float4 v = xp[t + i*256];
    float a[4] = {v.x, v.y, v.z, v.w};
    #pragma unroll
    for(int j=0;j<4;j++){
      float xx = a[j];
      vmin = fminf(vmin, xx); vmax = fmaxf(vmax, xx);
      float p = 1.f/(1.f + expf(-xx));
      sabs += fabsf(p - 0.5f);
      cnt += (xx > 0.f) ? 1.f : 0.f;   // sigmoid(x)>0.5 <=> x>0
    }
  }
  vmin = waveReduceMin(vmin); vmax = waveReduceMax(vmax);
  sabs = waveReduceSum(sabs); cnt = waveReduceSum(cnt);
  __shared__ float ls[4][4];
  int wid = t>>6, lane = t&63;
  if(lane==0){ ls[0][wid]=vmin; ls[1][wid]=vmax; ls[2][wid]=sabs; ls[3][wid]=cnt; }
  __syncthreads();
  if(t==0){
    float m=ls[0][0], M=ls[1][0], S=ls[2][0], C=ls[3][0];
    #pragma unroll
    for(int i=1;i<4;i++){ m=fminf(m,ls[0][i]); M=fmaxf(M,ls[1][i]); S+=ls[2][i]; C+=ls[3][i]; }
    float* o = p1 + (size_t)blockIdx.x*4;
    o[0]=m; o[1]=M; o[2]=S; o[3]=C;
  }
}

// Reduce pass-1 partials; compute lo, inv=1/(hi-lo+eps), weight w
__global__ __launch_bounds__(64) void k_stats2(const float* __restrict__ p1, float* __restrict__ stats){
  int s = blockIdx.x, t = threadIdx.x;
  const float* o = p1 + ((size_t)s*64 + t)*4;
  float m=o[0], M=o[1], S=o[2], C=o[3];
  m = waveReduceMin(m); M = waveReduceMax(M);
  S = waveReduceSum(S); C = waveReduceSum(C);
  if(t==0){
    float conf = S/(float)NPIX, area = C/(float)NPIX;
    float w = 0.4f;
    if(conf < 0.3f)  w *= 2.0f;
    if(area < 0.05f) w *= 1.5f;
    if(conf > 0.4f && area > 0.1f) w *= 0.5f;
    float d = M - m + 1e-8f;
    float* st = stats + s*4;
    st[0]=m; st[1]=1.0f/d; st[2]=w; st[3]=0.f;
  }
}

// Pass 2: binary flags -> row/col any-bits, binary count, sum(pn^2)
__global__ __launch_bounds__(256) void k_flags(const float* __restrict__ x, const float* __restrict__ stats,
    unsigned* __restrict__ rowbits, unsigned* __restrict__ colbits, float* __restrict__ p2){
  int s = blockIdx.x >> 6, blk = blockIdx.x & 63;
  int t = threadIdx.x;
  float lo = stats[s*4+0], inv = stats[s*4+1];
  const float4* xp = (const float4*)(x + (size_t)s*NPIX + (size_t)blk*ROWS_PER_BLK*WW);
  __shared__ unsigned colw[32];
  __shared__ unsigned rowf;
  __shared__ float ls[2][4];
  if(t<32) colw[t]=0;
  if(t==0) rowf=0;
  __syncthreads();
  float cnt=0.f, pn2=0.f;
  unsigned cb4 = 0, myrow = 0;
  #pragma unroll
  for(int r=0;r<ROWS_PER_BLK;r++){
    float4 v = xp[r*256 + t];       // thread t owns cols 4t..4t+3
    float a[4]={v.x,v.y,v.z,v.w};
    unsigned bits=0;
    #pragma unroll
    for(int j=0;j<4;j++){
      float pn = (a[j]-lo)*inv;
      pn2 += pn*pn;
      if(pn > 0.5f){ bits |= (1u<<j); cnt += 1.f; }
    }
    cb4 |= bits;
    if(bits) myrow |= (1u<<r);
  }
  if(cb4)   atomicOr(&colw[t>>3], cb4 << ((t&7)*4));
  if(myrow) atomicOr(&rowf, myrow);
  cnt = waveReduceSum(cnt); pn2 = waveReduceSum(pn2);
  int wid=t>>6, lane=t&63;
  if(lane==0){ ls[0][wid]=cnt; ls[1][wid]=pn2; }
  __syncthreads();
  if(t<32 && colw[t]) atomicOr(&colbits[s*32+t], colw[t]);
  if(t==0){
    float C=ls[0][0]+ls[0][1]+ls[0][2]+ls[0][3];
    float P=ls[1][0]+ls[1][1]+ls[1][2]+ls[1][3];
    float* o = p2 + ((size_t)s*64+blk)*2; o[0]=C; o[1]=P;
    if(rowf) atomicOr(&rowbits[s*32 + (blk>>1)], rowf << ((blk&1)*16));
  }
}

// Per sample: rect bounds from bits, area, valid, totals
__global__ __launch_bounds__(64) void k_rect(const float* __restrict__ p2, const unsigned* __restrict__ rowbits,
    const unsigned* __restrict__ colbits, float* __restrict__ rect){
  int s = blockIdx.x, t = threadIdx.x;
  const float* o = p2 + ((size_t)s*64 + t)*2;
  float C=o[0], P=o[1];
  C = waveReduceSum(C); P = waveReduceSum(P);
  if(t==0){
    int r0=-1,r1=-1,c0=-1,c1=-1;
    for(int w=0;w<32;w++){
      unsigned rb = rowbits[s*32+w];
      if(rb){ if(r0<0) r0 = w*32 + (__ffs(rb)-1); r1 = w*32 + (31-__clz((int)rb)); }
      unsigned cb = colbits[s*32+w];
      if(cb){ if(c0<0) c0 = w*32 + (__ffs(cb)-1); c1 = w*32 + (31-__clz((int)cb)); }
    }
    int anyb = (r0>=0);
    float area = anyb ? (float)((r1-r0+1)*(c1-c0+1)) : 0.f;
    float valid = (anyb && area != C) ? 1.f : 0.f;  // binary subset of rect: differ iff area>count
    float* rc = rect + s*8;
    ((int*)rc)[0]=r0; ((int*)rc)[1]=r1; ((int*)rc)[2]=c0; ((int*)rc)[3]=c1;
    rc[4]=area; rc[5]=valid; rc[6]=C; rc[7]=P;
  }
}

// Pass 3: sum of pn over rect
__global__ __launch_bounds__(256) void k_rectsum(const float* __restrict__ x, const float* __restrict__ stats,
    const float* __restrict__ rect, float* __restrict__ p3){
  int s = blockIdx.x >> 6, blk = blockIdx.x & 63;
  int t = threadIdx.x;
  const float* rc = rect + s*8;
  int r0=((const int*)rc)[0], r1=((const int*)rc)[1], c0=((const int*)rc)[2], c1=((const int*)rc)[3];
  float lo = stats[s*4+0], inv = stats[s*4+1];
  int rowbase = blk*ROWS_PER_BLK;
  float S=0.f;
  if(r0>=0 && rowbase<=r1 && rowbase+ROWS_PER_BLK-1>=r0){
    const float4* xp = (const float4*)(x + (size_t)s*NPIX + (size_t)rowbase*WW);
    int ra = max(r0-rowbase, 0), rb = min(r1-rowbase, ROWS_PER_BLK-1);
    for(int r=ra;r<=rb;r++){
      float4 v = xp[r*256 + t];
      float a[4]={v.x,v.y,v.z,v.w};
      #pragma unroll
      for(int j=0;j<4;j++){
        int c = 4*t+j;
        if(c>=c0 && c<=c1) S += (a[j]-lo)*inv;
      }
    }
  }
  S = waveReduceSum(S);
  __shared__ float ls[4];
  if((t&63)==0) ls[t>>6]=S;
  __syncthreads();
  if(t==0) p3[(size_t)s*64+blk] = ls[0]+ls[1]+ls[2]+ls[3];
}

// Final combine across samples
__global__ __launch_bounds__(256) void k_final(const float* __restrict__ p3, const float* __restrict__ rect,
    const float* __restrict__ stats, float* __restrict__ out, int B){
  __shared__ float srect[32];
  int t = threadIdx.x;
  int s = t>>3, k = t&7;
  if(s < B){
    float v = 0.f;
    #pragma unroll
    for(int i=0;i<8;i++) v += p3[(size_t)s*64 + k*8 + i];
    for(int off=4; off; off>>=1) v += __shfl_down(v, off, 8);
    if(k==0) srect[s] = v;
  }
  __syncthreads();
  if(t < 32){
    float loss = 0.f, val = 0.f;
    if(t < B){
      const float* rc = rect + t*8;
      float area=rc[4]; val=rc[5]; float P=rc[7];
      float S = srect[t];
      float base = (P - 2.f*S + area) / (float)NPIX;
      float w = stats[t*4+2];
      loss = base * w * val;
    }
    for(int off=16; off; off>>=1){ loss += __shfl_down(loss, off, 32); val += __shfl_down(val, off, 32); }
    if(t==0) out[0] = (val > 0.f) ? (loss / fmaxf(val, 1.f)) : 0.f;
  }
}

extern "C" void kernel_launch(void* const* d_in, const int* in_sizes, int n_in,
                              void* d_out, int out_size, void* d_ws, size_t ws_size,
                              hipStream_t stream) {
  const float* x = (const float*)d_in[0];
  int B = in_sizes[0] / NPIX;   // 32
  char* ws = (char*)d_ws;
  float*    p1      = (float*)(ws + 0);        // B*64*4 floats = 32768 B
  float*    stats   = (float*)(ws + 32768);    // B*4 floats (pad to 1024)
  unsigned* rowbits = (unsigned*)(ws + 33792); // B*32 u32 = 4096 B
  unsigned* colbits = (unsigned*)(ws + 37888); // 4096 B
  float*    p2      = (float*)(ws + 41984);    // B*64*2 floats = 16384 B
  float*    rect    = (float*)(ws + 58368);    // B*8 floats = 1024 B
  float*    p3      = (float*)(ws + 59392);    // B*64 floats = 8192 B
  float*    out     = (float*)d_out;

  hipMemsetAsync(rowbits, 0, 8192, stream);    // rowbits+colbits (atomicOr targets)
  k_stats1 <<<B*NB, 256, 0, stream>>>(x, p1);
  k_stats2 <<<B,    64,  0, stream>>>(p1, stats);
  k_flags  <<<B*NB, 256, 0, stream>>>(x, stats, rowbits, colbits, p2);
  k_rect   <<<B,    64,  0, stream>>>(p2, rowbits, colbits, rect);
  k_rectsum<<<B*NB, 256, 0, stream>>>(x, stats, rect, p3);
  k_final  <<<1,    256, 0, stream>>>(p3, rect, stats, out, B);
}

// Round 2
// 89.014 us; speedup vs baseline: 1.0467x; 1.0467x over previous
//
#include <hip/hip_runtime.h>

#define HH 1024
#define WW 1024
#define NPIX (HH*WW)
#define NRB 64          // rowblocks per sample (16 rows each)
#define EPSF 1e-8f

__device__ inline float wrsum(float v){ for(int o=32;o;o>>=1) v += __shfl_down(v,o); return v; }
__device__ inline float wrmin(float v){ for(int o=32;o;o>>=1) v = fminf(v,__shfl_down(v,o)); return v; }
__device__ inline float wrmax(float v){ for(int o=32;o;o>>=1) v = fmaxf(v,__shfl_down(v,o)); return v; }

// ---- Pass 1 (the ONLY full-data pass) ----
// Block = (sample s, rowblock rb of 16 rows). Thread t owns cols 4t..4t+3.
// Produces: per-(s,rb,col) {sum, min, max}; per-(s,row) max; per-(s,rb) partials
// of {min, max, sum|sigmoid-0.5|, count(x>0), sum x, sum x^2}.
__global__ __launch_bounds__(256) void k_pass1(const float* __restrict__ x,
    float* __restrict__ CSx, float* __restrict__ CMin, float* __restrict__ CMax,
    float* __restrict__ RM, float* __restrict__ p1){
  int s = blockIdx.x >> 6, rb = blockIdx.x & 63;
  int t = threadIdx.x;
  const float4* xp = (const float4*)(x + (size_t)s*NPIX + (size_t)rb*16*WW);
  float sabs=0.f, cnt=0.f, sx=0.f, sxx=0.f;
  float cmin[4]={INFINITY,INFINITY,INFINITY,INFINITY};
  float cmax[4]={-INFINITY,-INFINITY,-INFINITY,-INFINITY};
  float csum[4]={0.f,0.f,0.f,0.f};
  float rm[16];
  #pragma unroll
  for(int r=0;r<16;r++){
    float4 v = xp[r*256 + t];
    float a[4]={v.x,v.y,v.z,v.w};
    float rmx = -INFINITY;
    #pragma unroll
    for(int j=0;j<4;j++){
      float xx = a[j];
      rmx = fmaxf(rmx, xx);
      cmin[j] = fminf(cmin[j], xx);
      cmax[j] = fmaxf(cmax[j], xx);
      csum[j] += xx;
      sx += xx; sxx += xx*xx;
      float p = 1.f/(1.f + expf(-xx));
      sabs += fabsf(p - 0.5f);
      cnt += (xx > 0.f) ? 1.f : 0.f;   // sigmoid(x)>0.5 <=> x>0
    }
    rm[r] = rmx;
  }
  // column summary stores (coalesced float4)
  size_t cbase = ((size_t)s*NRB + rb)*WW + 4*t;
  *(float4*)(CSx  + cbase) = make_float4(csum[0],csum[1],csum[2],csum[3]);
  *(float4*)(CMin + cbase) = make_float4(cmin[0],cmin[1],cmin[2],cmin[3]);
  *(float4*)(CMax + cbase) = make_float4(cmax[0],cmax[1],cmax[2],cmax[3]);

  float vmin = fminf(fminf(cmin[0],cmin[1]), fminf(cmin[2],cmin[3]));
  float vmax = fmaxf(fmaxf(cmax[0],cmax[1]), fmaxf(cmax[2],cmax[3]));
  vmin = wrmin(vmin); vmax = wrmax(vmax);
  sabs = wrsum(sabs); cnt = wrsum(cnt); sx = wrsum(sx); sxx = wrsum(sxx);

  __shared__ float sred[6][4];
  __shared__ float rowls[4][16];
  int wid = t>>6, lane = t&63;
  if(lane==0){ sred[0][wid]=vmin; sred[1][wid]=vmax; sred[2][wid]=sabs;
               sred[3][wid]=cnt;  sred[4][wid]=sx;   sred[5][wid]=sxx; }
  #pragma unroll
  for(int r=0;r<16;r++){
    float m = wrmax(rm[r]);
    if(lane==0) rowls[wid][r] = m;
  }
  __syncthreads();
  if(t<16)
    RM[(size_t)s*HH + rb*16 + t] =
      fmaxf(fmaxf(rowls[0][t],rowls[1][t]), fmaxf(rowls[2][t],rowls[3][t]));
  if(t==0){
    float* o = p1 + ((size_t)s*NRB + rb)*8;
    o[0] = fminf(fminf(sred[0][0],sred[0][1]), fminf(sred[0][2],sred[0][3]));
    o[1] = fmaxf(fmaxf(sred[1][0],sred[1][1]), fmaxf(sred[1][2],sred[1][3]));
    o[2] = sred[2][0]+sred[2][1]+sred[2][2]+sred[2][3];
    o[3] = sred[3][0]+sred[3][1]+sred[3][2]+sred[3][3];
    o[4] = sred[4][0]+sred[4][1]+sred[4][2]+sred[4][3];
    o[5] = sred[5][0]+sred[5][1]+sred[5][2]+sred[5][3];
  }
}

// ---- Pass 2: per-sample stats + rect bounds (reads only summaries) ----
__global__ __launch_bounds__(256) void k_pass2(const float* __restrict__ p1,
    const float* __restrict__ RM, const float* __restrict__ CMax,
    int* __restrict__ rectI, float* __restrict__ rectF){
  int s = blockIdx.x, t = threadIdx.x;
  __shared__ float bc[8];
  __shared__ int ext[4];          // r0min, r1max, c0min, c1max
  if(t==0){ ext[0]=0x7fffffff; ext[1]=-1; ext[2]=0x7fffffff; ext[3]=-1; }
  if(t<64){
    const float* o = p1 + ((size_t)s*NRB + t)*8;
    float m=o[0], M=o[1], S=o[2], C=o[3], X=o[4], XX=o[5];
    m=wrmin(m); M=wrmax(M); S=wrsum(S); C=wrsum(C); X=wrsum(X); XX=wrsum(XX);
    if(t==0){
      float lo=m, d=M-m+EPSF, inv=1.f/d, T=lo+0.5f*d;
      float conf = S/(float)NPIX, area = C/(float)NPIX;
      float w = 0.4f;
      if(conf < 0.3f)  w *= 2.0f;
      if(area < 0.05f) w *= 1.5f;
      if(conf > 0.4f && area > 0.1f) w *= 0.5f;
      float sumpn2 = inv*inv*(XX - 2.f*lo*X + (float)NPIX*lo*lo);
      bc[0]=lo; bc[1]=inv; bc[2]=T; bc[3]=w; bc[4]=sumpn2;
    }
  }
  __syncthreads();
  float T = bc[2];
  { // row extents: 4 rows per thread
    int rlo=0x7fffffff, rhi=-1;
    #pragma unroll
    for(int i=0;i<4;i++){
      int r = t*4+i;
      if(RM[(size_t)s*HH + r] > T){ rlo = min(rlo,r); rhi = max(rhi,r); }
    }
    if(rhi>=0){ atomicMin(&ext[0],rlo); atomicMax(&ext[1],rhi); }
  }
  { // col extents: reduce CMax over 64 rowblocks, 4 cols per thread
    const float4* cm = (const float4*)(CMax + (size_t)s*NRB*WW) + t;
    float4 mx = cm[0];
    #pragma unroll 4
    for(int rb=1; rb<NRB; rb++){
      float4 v = cm[rb*256];
      mx.x=fmaxf(mx.x,v.x); mx.y=fmaxf(mx.y,v.y);
      mx.z=fmaxf(mx.z,v.z); mx.w=fmaxf(mx.w,v.w);
    }
    float a[4]={mx.x,mx.y,mx.z,mx.w};
    int clo=0x7fffffff, chi=-1;
    #pragma unroll
    for(int j=0;j<4;j++) if(a[j] > T){ int c=4*t+j; clo=min(clo,c); chi=max(chi,c); }
    if(chi>=0){ atomicMin(&ext[2],clo); atomicMax(&ext[3],chi); }
  }
  __syncthreads();
  if(t==0){
    int anyb = (ext[1] >= 0);
    rectI[s*4+0] = anyb ? ext[0] : -1;
    rectI[s*4+1] = ext[1];
    rectI[s*4+2] = anyb ? ext[2] : -1;
    rectI[s*4+3] = ext[3];
    rectF[s*8+0]=bc[0]; rectF[s*8+1]=bc[1]; rectF[s*8+2]=bc[2];
    rectF[s*8+3]=bc[3]; rectF[s*8+4]=bc[4];
  }
}

// ---- Pass 3: sum(x) and min(x) over the rect, from summaries + boundary rows ----
__global__ __launch_bounds__(256) void k_pass3(const float* __restrict__ x,
    const float* __restrict__ CSx, const float* __restrict__ CMin,
    const int* __restrict__ rectI, float* __restrict__ p3){
  int s = blockIdx.x >> 3, chunk = blockIdx.x & 7;
  int t = threadIdx.x;
  int r0=rectI[s*4], r1=rectI[s*4+1], c0=rectI[s*4+2], c1=rectI[s*4+3];
  float sum=0.f, mn=INFINITY;
  if(r0 >= 0){
    for(int rb=chunk*8; rb<chunk*8+8; rb++){
      int ra=rb*16, rz=ra+15;
      bool full = (ra >= r0) && (rz <= r1);
      if(full){
        const float* cs = CSx  + ((size_t)s*NRB + rb)*WW;
        const float* cm = CMin + ((size_t)s*NRB + rb)*WW;
        for(int c=c0+t; c<=c1; c+=256){ sum += cs[c]; mn = fminf(mn, cm[c]); }
      } else if(rz >= r0 && ra <= r1){
        int pa = max(ra,r0), pb = min(rz,r1);
        for(int r=pa; r<=pb; r++){
          const float* xr = x + (size_t)s*NPIX + (size_t)r*WW;
          for(int c=c0+t; c<=c1; c+=256){ float v=xr[c]; sum += v; mn = fminf(mn,v); }
        }
      }
    }
  }
  sum = wrsum(sum); mn = wrmin(mn);
  __shared__ float l1[4], l2[4];
  int wid=t>>6, lane=t&63;
  if(lane==0){ l1[wid]=sum; l2[wid]=mn; }
  __syncthreads();
  if(t==0){
    p3[(s*8+chunk)*2+0] = l1[0]+l1[1]+l1[2]+l1[3];
    p3[(s*8+chunk)*2+1] = fminf(fminf(l2[0],l2[1]), fminf(l2[2],l2[3]));
  }
}

// ---- Final: per-sample loss + weighted mean over valid samples ----
__global__ __launch_bounds__(256) void k_final(const float* __restrict__ p3,
    const int* __restrict__ rectI, const float* __restrict__ rectF,
    float* __restrict__ out, int B){
  int t = threadIdx.x;
  __shared__ float lossS[32], valS[32];
  int s = t>>3, k = t&7;
  float sum=0.f, mn=INFINITY;
  if(s < B){ sum = p3[(s*8+k)*2]; mn = p3[(s*8+k)*2+1]; }
  for(int o=4;o;o>>=1){ sum += __shfl_down(sum,o,8); mn = fminf(mn,__shfl_down(mn,o,8)); }
  if(s < B && k==0){
    int r0=rectI[s*4], r1=rectI[s*4+1], c0=rectI[s*4+2], c1=rectI[s*4+3];
    float lo=rectF[s*8], inv=rectF[s*8+1], T=rectF[s*8+2], w=rectF[s*8+3], spn2=rectF[s*8+4];
    float loss=0.f, val=0.f;
    if(r0 >= 0){
      float area = (float)((r1-r0+1)*(c1-c0+1));
      val = (mn <= T) ? 1.f : 0.f;          // exists rect pixel not binary
      float srpn = inv*(sum - area*lo);     // sum of pn over rect
      float base = (spn2 - 2.f*srpn + area)/(float)NPIX;
      loss = base * w * val;
    }
    lossS[s]=loss; valS[s]=val;
  }
  __syncthreads();
  if(t < 32){
    float l = (t<B)?lossS[t]:0.f, v = (t<B)?valS[t]:0.f;
    for(int o=16;o;o>>=1){ l += __shfl_down(l,o,32); v += __shfl_down(v,o,32); }
    if(t==0) out[0] = (v > 0.f) ? (l / fmaxf(v,1.f)) : 0.f;
  }
}

extern "C" void kernel_launch(void* const* d_in, const int* in_sizes, int n_in,
                              void* d_out, int out_size, void* d_ws, size_t ws_size,
                              hipStream_t stream) {
  const float* x = (const float*)d_in[0];
  int B = in_sizes[0] / NPIX;   // 32
  char* ws = (char*)d_ws;
  float* CSx  = (float*)(ws);                                  // 8 MB
  float* CMin = (float*)(ws + (size_t)8*1024*1024);            // 8 MB
  float* CMax = (float*)(ws + (size_t)16*1024*1024);           // 8 MB
  float* RM   = (float*)(ws + (size_t)24*1024*1024);           // 128 KB
  float* p1   = (float*)(ws + (size_t)24*1024*1024 + 131072);  // 64 KB
  int*   rectI= (int*)  (ws + (size_t)24*1024*1024 + 196608);  // 512 B (pad 4K)
  float* rectF= (float*)(ws + (size_t)24*1024*1024 + 200704);  // 1 KB (pad 4K)
  float* p3   = (float*)(ws + (size_t)24*1024*1024 + 204800);  // 2 KB
  float* out  = (float*)d_out;

  k_pass1<<<B*NRB, 256, 0, stream>>>(x, CSx, CMin, CMax, RM, p1);
  k_pass2<<<B,     256, 0, stream>>>(p1, RM, CMax, rectI, rectF);
  k_pass3<<<B*8,   256, 0, stream>>>(x, CSx, CMin, rectI, p3);
  k_final<<<1,     256, 0, stream>>>(p3, rectI, rectF, out, B);
}